// Round 14
// baseline (17.554 us; speedup 1.0000x reference)
//
#include <hip/hip_runtime.h>

constexpr int N = 512;
constexpr int D = 128;
constexpr float MARGIN = 1.0f;
constexpr float EPS_T = 1e-16f;

// Main: 1 anchor/block, 512 blocks (= 2 blocks/CU: two INDEPENDENT barrier
// domains per CU so one block's phase stall hides under the other's work —
// the untested cell: R5 had 2 blocks/CU + long chain, R12 short chain + 1).
//  P1: 4 passes, 2 rows/thread/pass, 8 lanes/row (full 128-B coalescing).
//      Per-row math + xor(1,2,4) tree bitwise-match R5/R9 (absmax-0 proven).
//  P2: all 8 waves ballot-compact the positive distances (ascending-j).
//  P3: thread's k (= tid) hinges over ~16 positives.
//  P4: fixed-tree f64 reduction -> partial[4*blk + {0,1,2}].
// Final: single wave, no LDS, no barrier.
__global__ __launch_bounds__(512, 4) void triplet_main_k(
    const float* __restrict__ emb, const int* __restrict__ labels,
    double* __restrict__ partial)
{
    __shared__ float  drow[N];
    __shared__ float  posd[128];
    __shared__ int    cnt[8];
    __shared__ int    npos_s;
    __shared__ double red[24];   // [0..7]=sum, [8..15]=npos, [16..23]=ntrip

    const int i    = blockIdx.x;
    const int tid  = threadIdx.x;
    const int lane = tid & 63;
    const int wid  = tid >> 6;
    const int sub  = tid & 7;    // lane-in-row
    const int grp  = tid >> 3;   // 0..63 row-group

    // anchor -> registers (8-lane broadcast loads)
    const float4* ea = reinterpret_cast<const float4*>(emb + (size_t)i * D);
    float4 A0[4];
    #pragma unroll
    for (int c = 0; c < 4; ++c) A0[c] = ea[sub + 8 * c];

    const int lk = labels[tid];        // this thread's k-label
    const int li = labels[i];          // uniform broadcast

    // ---- P1: 4 passes, 2 rows/thread/pass ----
    #pragma unroll 2
    for (int p = 0; p < 4; ++p) {
        const int r0 = p * 128 + grp;
        const int r1 = r0 + 64;
        const float4* er0 = reinterpret_cast<const float4*>(emb + (size_t)r0 * D);
        const float4* er1 = reinterpret_cast<const float4*>(emb + (size_t)r1 * D);
        float4 V0[4], V1[4];
        #pragma unroll
        for (int c = 0; c < 4; ++c) { V0[c] = er0[sub + 8 * c]; V1[c] = er1[sub + 8 * c]; }
        float sq0 = 0.f, sq1 = 0.f;
        #pragma unroll
        for (int c = 0; c < 4; ++c) {
            float d0 = A0[c].x - V0[c].x, d1 = A0[c].y - V0[c].y;
            float d2 = A0[c].z - V0[c].z, d3 = A0[c].w - V0[c].w;
            sq0 += d0 * d0 + d1 * d1 + d2 * d2 + d3 * d3;
            d0 = A0[c].x - V1[c].x; d1 = A0[c].y - V1[c].y;
            d2 = A0[c].z - V1[c].z; d3 = A0[c].w - V1[c].w;
            sq1 += d0 * d0 + d1 * d1 + d2 * d2 + d3 * d3;
        }
        sq0 += __shfl_xor(sq0, 1); sq1 += __shfl_xor(sq1, 1);
        sq0 += __shfl_xor(sq0, 2); sq1 += __shfl_xor(sq1, 2);
        sq0 += __shfl_xor(sq0, 4); sq1 += __shfl_xor(sq1, 4);
        if (sub == 0) {
            drow[r0] = (sq0 > 0.f) ? sqrtf(sq0) : 0.f;   // safe sqrt
            drow[r1] = (sq1 > 0.f) ? sqrtf(sq1) : 0.f;
        }
    }
    __syncthreads();

    // ---- P2: parallel compaction, all 8 waves (ascending-j kept) ----
    const int j = tid;
    const bool pr = (labels[j] == li) && (j != i);
    const unsigned long long m = __ballot(pr);
    if (lane == 0) cnt[wid] = __popcll(m);
    __syncthreads();
    int base = 0;
    #pragma unroll
    for (int w = 0; w < 8; ++w) base += (w < wid) ? cnt[w] : 0;
    if (pr) posd[base + __popcll(m & ((1ull << lane) - 1ull))] = drow[j];
    if (tid == 0) {
        int t = 0;
        #pragma unroll
        for (int w = 0; w < 8; ++w) t += cnt[w];
        npos_s = t;
    }
    __syncthreads();

    // ---- P3: hinge accumulation, k = tid ----
    const int   npos = npos_s;
    const float dik  = drow[tid];
    double sum = 0.0;
    int np_i = 0, nt_i = 0;
    if (lk != li) {
        for (int p = 0; p < npos; ++p) {
            const float t = (posd[p] - dik) + MARGIN;  // reference op order
            if (t > EPS_T) { sum += (double)t; ++np_i; }
        }
        nt_i = npos;
    }

    // ---- P4: fixed-tree reduction ----
    double s = sum, p = (double)np_i, t = (double)nt_i;
    #pragma unroll
    for (int off = 32; off > 0; off >>= 1) {
        s += __shfl_down(s, off);
        p += __shfl_down(p, off);
        t += __shfl_down(t, off);
    }
    if (lane == 0) { red[wid] = s; red[8 + wid] = p; red[16 + wid] = t; }
    __syncthreads();
    if (tid == 0) {
        double S = 0.0, P = 0.0, T = 0.0;
        #pragma unroll
        for (int w = 0; w < 8; ++w) { S += red[w]; P += red[8 + w]; T += red[16 + w]; }
        partial[4 * blockIdx.x + 0] = S;
        partial[4 * blockIdx.x + 1] = P;
        partial[4 * blockIdx.x + 2] = T;
    }
}

// Single-wave finalizer: no LDS, no barrier.
__global__ __launch_bounds__(64) void triplet_final_k(
    const double* __restrict__ partial, float* __restrict__ out)
{
    const int lane = threadIdx.x;
    double a = 0.0, b = 0.0, c = 0.0;
    #pragma unroll
    for (int bk = lane; bk < N; bk += 64) {
        a += partial[4 * bk + 0];
        b += partial[4 * bk + 1];
        c += partial[4 * bk + 2];
    }
    #pragma unroll
    for (int off = 32; off > 0; off >>= 1) {
        a += __shfl_down(a, off);
        b += __shfl_down(b, off);
        c += __shfl_down(c, off);
    }
    if (lane == 0) {
        out[0] = (float)(a / (b + 1e-16));  // loss
        out[1] = (float)(b / (c + 1e-16));  // fraction_positive
    }
}

extern "C" void kernel_launch(void* const* d_in, const int* in_sizes, int n_in,
                              void* d_out, int out_size, void* d_ws, size_t ws_size,
                              hipStream_t stream) {
    const float* emb   = (const float*)d_in[0];   // [512,128] f32
    const int*   lab   = (const int*)d_in[1];     // [512] i32
    float*       out   = (float*)d_out;           // [2] f32: loss, fraction_positive
    double*      parts = (double*)d_ws;           // 4*N doubles = 16 KB

    triplet_main_k<<<N, 512, 0, stream>>>(emb, lab, parts);
    triplet_final_k<<<1, 64, 0, stream>>>(parts, out);
}